// Round 1
// 683.497 us; speedup vs baseline: 1.1671x; 1.1671x over previous
//
#include <hip/hip_runtime.h>
#include <hip/hip_bf16.h>
#include <float.h>
#include <cstdint>

// ---------------------------------------------------------------------------
// RCSLS: out = ( topk10sum(X_trans@Z_tgt^T)/10 + topk10sum(Y_tgt@Z_trans^T)/10
//               - 2*sum(X_trans*Y_tgt) ) / 4096
// B=4096, N=32768, d=512, k=10.  Inputs f32; GEMMs in bf16 MFMA 16x16x32.
//
// R5 GEMM rewrite: 256x256 tile, 8 waves (2M x 4N), K pipelined as 16
// sub-tiles of K=32 through a 4-slot (4 x 32KB = 128KB) LDS rotation.
// Counted s_waitcnt vmcnt(8) -- never drained to 0 in the main loop -- raw
// s_barrier, register-double-buffered A fragments, s_setprio around the
// 32-MFMA cluster (T3+T4+T5 from the technique catalog).
// Staging keeps the verified "segment order" layout: global_load_lds writes
// exactly in MFMA fragment lane order -> conflict-free LDS reads AND writes.
// MFMA operands are SWAPPED (mfma(b_frag, a_frag)): each lane holds 16 cols
// of ONE output row, so the per-(row, 64-col-window) top-4 runs entirely in
// registers (packed-u16 insertion network + two shfl_xor bitonic merges).
// No LDS C-dump, no scan, no post-loop syncthreads. P layout & merge kernel
// unchanged; sortable-u16 mapping bit-identical to the previous version.
//
// Pipeline invariants (per wave, 4 gloads per sub-tile):
//   prologue: stage S0..S3, vmcnt(8) [S0,S1 landed], barrier, read af(S0)
//   iter J:   read bfr(S_J) | prefetch af(S_{J+1}) | MFMA x32 (S_J)
//             J<12 : lgkmcnt(8) [all slot-J reads done], barrier,
//                    stage S_{J+4} -> slot J%4, vmcnt(8) [S_{J+2} landed],
//                    barrier (publishes S_{J+2} for iter J+1's prefetch)
//             J=12 : vmcnt(4) [S14 landed], barrier
//             J=13 : vmcnt(0) [S15 landed], barrier
// ---------------------------------------------------------------------------

#define B_ROWS 4096
#define N_COLS 32768
#define D_K    512
#define NCHUNK (N_COLS / 128)   // 256 chunks of 128 cols (P layout, unchanged)

typedef __bf16 bf16x8 __attribute__((ext_vector_type(8)));
typedef float  f32x4  __attribute__((ext_vector_type(4)));
typedef unsigned short u16x2 __attribute__((ext_vector_type(2)));

__device__ __forceinline__ unsigned short f2bf(float f) {
    unsigned int u = __float_as_uint(f);
    u += 0x7FFFu + ((u >> 16) & 1u);   // RNE
    return (unsigned short)(u >> 16);
}
// monotone map: f32 order == unsigned order of (f2sort32(f)>>16).
// (f2sort32(f)>>16) is bit-identical to the previous kernel's f2sort(f).
__device__ __forceinline__ unsigned f2sort32(float f) {
    unsigned u = __float_as_uint(f);
    u += 0x7FFFu + ((u >> 16) & 1u);               // RNE to bf16 in high half
    return u ^ (0x80000000u | (unsigned)((int)u >> 31));
}
__device__ __forceinline__ float sort2f(unsigned int y) {
    unsigned int x = (y & 0x8000u) ? (y ^ 0x8000u) : (~y & 0xFFFFu);
    return __uint_as_float(x << 16);
}
__device__ __forceinline__ unsigned umax(unsigned a, unsigned b) { return a > b ? a : b; }
__device__ __forceinline__ unsigned umin(unsigned a, unsigned b) { return a < b ? a : b; }

__device__ __forceinline__ void gload_lds16(const void* g, void* l) {
    __builtin_amdgcn_global_load_lds(
        (const __attribute__((address_space(1))) unsigned int*)(uintptr_t)g,
        (__attribute__((address_space(3))) unsigned int*)(uintptr_t)l,
        16, 0, 0);
}

// ---- zero the 3 scalar accumulators -----------------------------------------
__global__ void zero_scalars(float* sc) {
    if (threadIdx.x < 3) sc[threadIdx.x] = 0.0f;
}

// ---- fused f32->bf16 conversion (4 arrays) + dot(X,Y); grid.y selects ------
__global__ void prep_kernel(const float4* __restrict__ X,
                            const float4* __restrict__ Y,
                            const float4* __restrict__ Zt,
                            const float4* __restrict__ Ztr,
                            ushort4* __restrict__ A0, ushort4* __restrict__ A1,
                            ushort4* __restrict__ B0, ushort4* __restrict__ B1,
                            float* __restrict__ dotacc) {
    const int z = blockIdx.y;
    int i = blockIdx.x * 256 + threadIdx.x;
    const int stride = gridDim.x * 256;
    if (z == 0) {
        float s = 0.0f;
        for (; i < B_ROWS * D_K / 4; i += stride) {
            float4 x = X[i], y = Y[i];
            ushort4 u; u.x = f2bf(x.x); u.y = f2bf(x.y);
            u.z = f2bf(x.z); u.w = f2bf(x.w);
            A0[i] = u;
            s += x.x * y.x + x.y * y.y + x.z * y.z + x.w * y.w;
        }
        for (int o = 32; o > 0; o >>= 1) s += __shfl_down(s, o);
        __shared__ float wsum[4];
        int lane = threadIdx.x & 63, w = threadIdx.x >> 6;
        if (lane == 0) wsum[w] = s;
        __syncthreads();
        if (threadIdx.x == 0)
            atomicAdd(dotacc, wsum[0] + wsum[1] + wsum[2] + wsum[3]);
    } else {
        const float4* src = (z == 1) ? Y : (z == 2) ? Zt : Ztr;
        ushort4* dst = (z == 1) ? A1 : (z == 2) ? B0 : B1;
        int n4 = (z == 1) ? (B_ROWS * D_K / 4) : (N_COLS * D_K / 4);
        for (; i < n4; i += stride) {
            float4 f = src[i];
            ushort4 u; u.x = f2bf(f.x); u.y = f2bf(f.y);
            u.z = f2bf(f.z); u.w = f2bf(f.w);
            dst[i] = u;
        }
    }
}

// ---- pipeline / epilogue macros --------------------------------------------
#define BARRIER()  asm volatile("s_barrier" ::: "memory")
#define VMCNT(N)   asm volatile("s_waitcnt vmcnt(" #N ")" ::: "memory")
#define LGKM(N)    asm volatile("s_waitcnt lgkmcnt(" #N ")" ::: "memory")
#define MEMFENCE() asm volatile("" ::: "memory")

// stage sub-tile T (K cols [T*32, T*32+32)) into slot T&3.
// wave w stages A segs {w, 8+w} and B segs {w, 8+w}; 1KB per wave-call,
// lane order == fragment order.
#define STAGE(T) do { \
    gload_lds16(gA0 + (T) * 32, smem + ((T) & 3) * 16384 + w * 512); \
    gload_lds16(gA1 + (T) * 32, smem + ((T) & 3) * 16384 + (8 + w) * 512); \
    gload_lds16(gB0 + (T) * 32, smem + ((T) & 3) * 16384 + 8192 + w * 512); \
    gload_lds16(gB1 + (T) * 32, smem + ((T) & 3) * 16384 + 8192 + (8 + w) * 512); \
} while (0)

#define LOAD_AF(ARR, SLOT) { _Pragma("unroll") for (int mi = 0; mi < 8; ++mi) \
    ARR[mi] = *(const bf16x8*)(smem + (SLOT) * 16384 + abase + mi * 512 + lane8); }

#define MFMA32(ARR) { __builtin_amdgcn_s_setprio(1); \
    _Pragma("unroll") for (int mi = 0; mi < 8; ++mi) { \
    _Pragma("unroll") for (int ni = 0; ni < 4; ++ni) { \
        acc[mi][ni] = __builtin_amdgcn_mfma_f32_16x16x32_bf16( \
            bfr[ni], ARR[mi], acc[mi][ni], 0, 0, 0); } } \
    __builtin_amdgcn_s_setprio(0); }

#define KSTEP(J) do { \
    bf16x8 bfr[4]; \
    _Pragma("unroll") for (int ni = 0; ni < 4; ++ni) \
        bfr[ni] = *(const bf16x8*)(smem + ((J) & 3) * 16384 + bbase + ni * 512 + lane8); \
    MEMFENCE(); \
    if ((J) & 1) { \
        if ((J) < 15) LOAD_AF(af0, ((J) + 1) & 3) \
        MFMA32(af1) \
    } else { \
        if ((J) < 15) LOAD_AF(af1, ((J) + 1) & 3) \
        MFMA32(af0) \
    } \
    if ((J) < 12)       { LGKM(8); BARRIER(); STAGE((J) + 4); VMCNT(8); BARRIER(); } \
    else if ((J) == 12) { VMCNT(4); BARRIER(); } \
    else if ((J) == 13) { VMCNT(0); BARRIER(); } \
} while (0)

#define CSWAP(a, b) { unsigned _hi = umax(a, b), _lo = umin(a, b); a = _hi; b = _lo; }
#define SORT4() { CSWAP(m0, m1); CSWAP(m2, m3); CSWAP(m0, m2); CSWAP(m1, m3); CSWAP(m1, m2); }
#define INS(V) { u16x2 _hi; \
    _hi = __builtin_elementwise_max(t0, V); V = __builtin_elementwise_min(t0, V); t0 = _hi; \
    _hi = __builtin_elementwise_max(t1, V); V = __builtin_elementwise_min(t1, V); t1 = _hi; \
    _hi = __builtin_elementwise_max(t2, V); V = __builtin_elementwise_min(t2, V); t2 = _hi; \
    _hi = __builtin_elementwise_max(t3, V); V = __builtin_elementwise_min(t3, V); t3 = _hi; }

// ---- 256x256 bf16 GEMM + in-register per-(row, 64-col) top-4 ---------------
// grid (2048, 2): y selects which GEMM. 512 threads = 8 waves (2M x 4N).
__global__ __launch_bounds__(512, 2)
void gemm_topk_kernel(const unsigned short* __restrict__ A0g,
                      const unsigned short* __restrict__ A1g,
                      const unsigned short* __restrict__ B0g,
                      const unsigned short* __restrict__ B1g,
                      uint2* __restrict__ P0, uint2* __restrict__ P1) {
    const unsigned short* A  = blockIdx.y ? A1g : A0g;
    const unsigned short* Bm = blockIdx.y ? B1g : B0g;
    uint2* P2 = blockIdx.y ? P1 : P0;

    __shared__ __align__(128) unsigned short smem[4 * 16384];  // 128 KiB

    const int tid   = threadIdx.x;
    const int lane  = tid & 63;
    const int w     = tid >> 6;       // wave 0..7
    const int wm    = w >> 2;         // 0..1 : 128-row half
    const int wn    = w & 3;          // 0..3 : 64-col window
    const int quad  = lane >> 4;
    const int mrow  = lane & 15;
    const int lane8 = lane * 8;

    // XCD swizzle: xcd owns a 16-col-block window; 8-block group stays in L2
    const int b      = blockIdx.x;
    const int xcd    = b & 7;
    const int ii     = b >> 3;            // 0..255
    const int cw     = ii & 7;
    const int rowblk = (ii >> 3) & 15;
    const int cg     = ii >> 7;           // 0..1
    const int bn     = xcd * 16 + cg * 8 + cw;   // 0..127
    const int row0   = rowblk * 256;
    const int col0   = bn * 256;

    // staging sources: wave w owns A rows {w*16.., 128+w*16..}, B likewise;
    // lane (quad,mrow) -> row +mrow, k-offset quad*8  (segment/lane order)
    const unsigned short* gA0 = A  + (size_t)(row0 + w * 16 + mrow) * D_K + quad * 8;
    const unsigned short* gA1 = gA0 + 128 * D_K;
    const unsigned short* gB0 = Bm + (size_t)(col0 + w * 16 + mrow) * D_K + quad * 8;
    const unsigned short* gB1 = gB0 + 128 * D_K;

    const int abase = wm * 4096;          // this wave's A seg base (shorts)
    const int bbase = 8192 + wn * 2048;   // this wave's B seg base

    f32x4 acc[8][4];
    #pragma unroll
    for (int mi = 0; mi < 8; ++mi)
        #pragma unroll
        for (int ni = 0; ni < 4; ++ni)
            acc[mi][ni] = (f32x4){0.f, 0.f, 0.f, 0.f};

    bf16x8 af0[8], af1[8];

    // ---- prologue ----
    STAGE(0); MEMFENCE();
    STAGE(1); MEMFENCE();
    STAGE(2); MEMFENCE();
    STAGE(3);
    VMCNT(8);        // S0, S1 landed (per wave)
    BARRIER();       // publish S0, S1
    LOAD_AF(af0, 0)  // prefetch A fragments of S0

    // ---- main loop: 16 K sub-tiles ----
    KSTEP(0);  KSTEP(1);  KSTEP(2);  KSTEP(3);
    KSTEP(4);  KSTEP(5);  KSTEP(6);  KSTEP(7);
    KSTEP(8);  KSTEP(9);  KSTEP(10); KSTEP(11);
    KSTEP(12); KSTEP(13); KSTEP(14); KSTEP(15);

    // ---- epilogue: per-row top-4 of this wave's 64-col window, in regs ----
    // swapped-operand mapping (derived from the verified C layout):
    //   X-row = row0 + wm*128 + mi*16 + mrow      (fixed per lane)
    //   col   = col0 + wn*64 + ni*16 + quad*4 + r
    // row's 64 cols live on lanes {mrow, mrow+16, mrow+32, mrow+48}.
    const int chunk = bn * 2 + (wn >> 1);
    const int half  = wn & 1;
    #pragma unroll
    for (int mi = 0; mi < 8; ++mi) {
        u16x2 t0 = {0, 0}, t1 = {0, 0}, t2 = {0, 0}, t3 = {0, 0};
        #pragma unroll
        for (int ni = 0; ni < 4; ++ni) {
            unsigned s0 = f2sort32(acc[mi][ni][0]);
            unsigned s1 = f2sort32(acc[mi][ni][1]);
            unsigned s2 = f2sort32(acc[mi][ni][2]);
            unsigned s3 = f2sort32(acc[mi][ni][3]);
            unsigned pa = (s0 >> 16) | (s1 & 0xFFFF0000u);
            unsigned pb = (s2 >> 16) | (s3 & 0xFFFF0000u);
            u16x2 v0 = *(u16x2*)&pa;
            u16x2 v1 = *(u16x2*)&pb;
            INS(v0); INS(v1);
        }
        // top-4 multiset of this lane's 16 values (chains sorted desc)
        unsigned m0 = umax((unsigned)t0.x, (unsigned)t3.y);
        unsigned m1 = umax((unsigned)t1.x, (unsigned)t2.y);
        unsigned m2 = umax((unsigned)t2.x, (unsigned)t1.y);
        unsigned m3 = umax((unsigned)t3.x, (unsigned)t0.y);
        SORT4();
        // bitonic merge with quad partners (lane^16, then lane^32)
        #pragma unroll
        for (int st = 0; st < 2; ++st) {
            unsigned pa = m0 | (m1 << 16);
            unsigned pb = m2 | (m3 << 16);
            unsigned qa = (unsigned)__shfl_xor((int)pa, st ? 32 : 16);
            unsigned qb = (unsigned)__shfl_xor((int)pb, st ? 32 : 16);
            unsigned ra = (qa >> 16) | (qa << 16);   // (p1, p0)
            unsigned rb = (qb >> 16) | (qb << 16);   // (p3, p2)
            u16x2 n0 = __builtin_elementwise_max(*(u16x2*)&pa, *(u16x2*)&rb);
            u16x2 n1 = __builtin_elementwise_max(*(u16x2*)&pb, *(u16x2*)&ra);
            m0 = n0.x; m1 = n0.y; m2 = n1.x; m3 = n1.y;
            SORT4();
        }
        if (quad == 0) {
            int row_g = row0 + wm * 128 + mi * 16 + mrow;
            P2[((size_t)row_g * NCHUNK + chunk) * 2 + half] =
                make_uint2(m0 | (m1 << 16), m2 | (m3 << 16));
        }
    }
}

// ---- per-row exact top-10 over 2048 u16 candidates; one wave per row --------
// grid (1024, 2): y selects which GEMM's P / accumulator.  (unchanged)
__global__ __launch_bounds__(256, 4)
void merge_topk_kernel(const unsigned int* __restrict__ P0,
                       const unsigned int* __restrict__ P1,
                       float* __restrict__ sc) {
    const int g    = blockIdx.y;
    const int lane = threadIdx.x & 63;
    const int w    = threadIdx.x >> 6;
    const int row  = blockIdx.x * 4 + w;
    const unsigned int* Rp = (g ? P1 : P0) + (size_t)row * (NCHUNK * 4); // 1024 u32

    u16x2 t[10];
    #pragma unroll
    for (int i = 0; i < 10; ++i) t[i] = (u16x2){0, 0};
    #pragma unroll 4
    for (int it = 0; it < 16; ++it) {
        unsigned int raw = Rp[lane + 64 * it];
        u16x2 v = *(u16x2*)&raw;
        #pragma unroll
        for (int i = 0; i < 10; ++i) {
            u16x2 hi = __builtin_elementwise_max(t[i], v);
            v = __builtin_elementwise_min(t[i], v);
            t[i] = hi;
        }
    }
    unsigned int wreg[10];
    #pragma unroll
    for (int i = 0; i < 10; ++i) {
        unsigned int mv = umax((unsigned int)t[i].x,
                               (unsigned int)t[9 - i].y);
        wreg[i] = (mv << 16) | ((unsigned int)lane << 4) | (unsigned int)i;
    }
    float sum10 = 0.0f;
    #pragma unroll
    for (int iter = 0; iter < 10; ++iter) {
        unsigned int mx = wreg[0];
        #pragma unroll
        for (int s = 1; s < 10; ++s) mx = umax(mx, wreg[s]);
        #pragma unroll
        for (int o = 32; o > 0; o >>= 1)
            mx = umax(mx, (unsigned int)__shfl_xor((int)mx, o));
        sum10 += sort2f(mx >> 16);
        #pragma unroll
        for (int s = 0; s < 10; ++s)
            if (wreg[s] == mx) wreg[s] = 0u;
    }
    if (lane == 0) atomicAdd(sc + 1 + g, sum10);
}

// ---- final scalar -----------------------------------------------------------
__global__ void finalize_kernel(const float* __restrict__ sc,
                                float* __restrict__ out) {
    if (threadIdx.x == 0) {
        float f = (sc[1] * 0.1f + sc[2] * 0.1f - 2.0f * sc[0]) * (1.0f / 4096.0f);
        out[0] = f;
    }
}

extern "C" void kernel_launch(void* const* d_in, const int* in_sizes, int n_in,
                              void* d_out, int out_size, void* d_ws, size_t ws_size,
                              hipStream_t stream) {
    const float* X_trans = (const float*)d_in[1];
    const float* Y_tgt   = (const float*)d_in[2];
    const float* Z_trans = (const float*)d_in[4];
    const float* Z_tgt   = (const float*)d_in[5];

    char* ws = (char*)d_ws;
    float* sc = (float*)ws;                                  // [0]=dot [1]=fk0 [2]=fk1
    unsigned short* A0 = (unsigned short*)(ws + 256);        // X_trans bf16 [4096,512]
    unsigned short* A1 = A0 + (size_t)B_ROWS * D_K;          // Y_tgt  bf16
    unsigned short* B0 = A1 + (size_t)B_ROWS * D_K;          // Z_tgt  bf16 [32768,512]
    unsigned short* B1 = B0 + (size_t)N_COLS * D_K;          // Z_trans bf16
    uint2* P0 = (uint2*)(B1 + (size_t)N_COLS * D_K);         // [4096][256][2] uint2
    uint2* P1 = P0 + (size_t)B_ROWS * NCHUNK * 2;

    zero_scalars<<<1, 64, 0, stream>>>(sc);

    dim3 pgrid(2048, 4);
    prep_kernel<<<pgrid, 256, 0, stream>>>(
        (const float4*)X_trans, (const float4*)Y_tgt,
        (const float4*)Z_tgt, (const float4*)Z_trans,
        (ushort4*)A0, (ushort4*)A1, (ushort4*)B0, (ushort4*)B1, sc + 0);

    dim3 ggrid(2048, 2);
    gemm_topk_kernel<<<ggrid, 512, 0, stream>>>(A0, A1, B0, B1, P0, P1);

    dim3 mgrid(B_ROWS / 4, 2);
    merge_topk_kernel<<<mgrid, 256, 0, stream>>>(
        (const unsigned int*)P0, (const unsigned int*)P1, sc);

    finalize_kernel<<<1, 64, 0, stream>>>(sc, (float*)d_out);
}